// Round 1
// baseline (2225.914 us; speedup 1.0000x reference)
//
#include <hip/hip_runtime.h>
#include <stdint.h>

#define T_STEPS 512
#define BATCH   128
#define HID     512
#define KTOT    1024
#define HPAIRS  (BATCH * 256)   // u64 packets per h buffer (2 bf16 per packet)

typedef __attribute__((ext_vector_type(8))) short          bf16x8;
typedef __attribute__((ext_vector_type(8))) unsigned short u16x8;
typedef __attribute__((ext_vector_type(4))) float          f32x4;

__device__ inline unsigned short f2bf(float f) {
    union { float f; unsigned u; } x; x.f = f;
    unsigned r = x.u + 0x7FFFu + ((x.u >> 16) & 1u);   // RNE
    return (unsigned short)(r >> 16);
}

__device__ inline float sigmoidf_(float x) { return 1.f / (1.f + __expf(-x)); }
__device__ inline float tanhf_(float x)    { float e = __expf(2.f * x); return 1.f - 2.f / (e + 1.f); }

// one-shot fp32 -> bf16 cast of the input sequence
__global__ void cast_x_kernel(const float* __restrict__ x, unsigned short* __restrict__ y, int n) {
    int i = (blockIdx.x * blockDim.x + threadIdx.x) * 8;
    if (i >= n) return;
    float4 a = *(const float4*)(x + i);
    float4 b = *(const float4*)(x + i + 4);
    u16x8 v;
    v[0] = f2bf(a.x); v[1] = f2bf(a.y); v[2] = f2bf(a.z); v[3] = f2bf(a.w);
    v[4] = f2bf(b.x); v[5] = f2bf(b.y); v[6] = f2bf(b.z); v[7] = f2bf(b.w);
    *(u16x8*)(y + i) = v;
}

// load 32B of x row-slice as packed bf16 (converting if source is fp32)
__device__ inline void load_x32(const float* xf, const unsigned short* xbf, int use_xbf,
                                size_t off, uint4& a, uint4& b) {
    if (use_xbf) {
        const uint4* p = (const uint4*)(xbf + off);
        a = p[0]; b = p[1];
    } else {
        const float4* p = (const float4*)(xf + off);
        float4 f0 = p[0], f1 = p[1], f2 = p[2], f3 = p[3];
        u16x8 v;
        v[0] = f2bf(f0.x); v[1] = f2bf(f0.y); v[2] = f2bf(f0.z); v[3] = f2bf(f0.w);
        v[4] = f2bf(f1.x); v[5] = f2bf(f1.y); v[6] = f2bf(f1.z); v[7] = f2bf(f1.w);
        a = *(uint4*)&v;
        u16x8 w;
        w[0] = f2bf(f2.x); w[1] = f2bf(f2.y); w[2] = f2bf(f2.z); w[3] = f2bf(f2.w);
        w[4] = f2bf(f3.x); w[5] = f2bf(f3.y); w[6] = f2bf(f3.z); w[7] = f2bf(f3.w);
        b = *(uint4*)&w;
    }
}

// Persistent LSTM. grid = 128 WGs (8 batch-groups x 16 col-groups), block = 512.
// h-exchange uses SELF-VALIDATING 64-bit packets {tag=t+1 (hi32), 2x bf16 (lo32)}:
// no flag array, no waitcnt(0) drain, no third barrier. Consumers poll the data
// directly; the next step's packet loads are pre-issued at the end of phase C so
// the straggler WG of each 16-WG group pays zero extra roundtrips.
// 2 barriers/step.
__global__ __launch_bounds__(512, 2) void lstm_kernel(
    const float* __restrict__ xf,
    const unsigned short* __restrict__ xbf,
    const float* __restrict__ Wf, const float* __restrict__ bfv,
    const float* __restrict__ Wi, const float* __restrict__ biv,
    const float* __restrict__ Wg, const float* __restrict__ bgv,
    const float* __restrict__ Wo, const float* __restrict__ bov,
    float* __restrict__ out,
    unsigned long long* __restrict__ hbuf,   // [2][128][256] u64 packets, bypass-access only
    int use_xbf)
{
    // comb rows padded to 1048 shorts; x in cols 0..511, h in 512..1023.
    __shared__ __align__(16) unsigned short comb[16][1048];
    __shared__ float gatesl[4][16][33];

    const int tid  = threadIdx.x;
    const int bgc  = blockIdx.x >> 4;    // batch group 0..7
    const int cg   = blockIdx.x & 15;    // col group 0..15
    const int w    = tid >> 6;
    const int lane = tid & 63;
    const int gate = w & 3;              // 0=f 1=i 2=g 3=o
    const int uh   = w >> 2;
    const int n    = lane & 15;
    const int quad = lane >> 4;
    const int unit = cg * 32 + uh * 16 + n;

    const float* Wp = (gate == 0) ? Wf : (gate == 1) ? Wi : (gate == 2) ? Wg : Wo;
    const float* bp = (gate == 0) ? bfv : (gate == 1) ? biv : (gate == 2) ? bgv : bov;
    const float bias = bp[unit];

    // ---- preload W slice into registers as bf16 B-fragments (once) ----
    bf16x8 wfr[32];
    const float* wrow = Wp + (size_t)unit * KTOT;
#pragma unroll
    for (int kk = 0; kk < 32; ++kk) {
        const float4* p = (const float4*)(wrow + kk * 32 + quad * 8);
        float4 a = p[0], b = p[1];
        u16x8 v;
        v[0] = f2bf(a.x); v[1] = f2bf(a.y); v[2] = f2bf(a.z); v[3] = f2bf(a.w);
        v[4] = f2bf(b.x); v[5] = f2bf(b.y); v[6] = f2bf(b.z); v[7] = f2bf(b.w);
        wfr[kk] = (bf16x8)v;
    }

    const int srow = tid >> 5;   // staging row 0..15 (wave w owns rows 2w, 2w+1)
    const int scol = tid & 31;   // 16 shorts (32B) per thread per row

    // cell-thread mapping: this thread owns (bc, uc) forever; c lives in a register
    const int bc = srow, uc = scol;
    float creg = 0.f;
    const int bglob = bgc * 16 + bc;
    const int uglob = cg * 32 + uc;
    const int bgrow = bgc * 16 + srow;   // == bglob

    const size_t xstride = (size_t)HID;

    // ---- prologue: stage x_0, zero h region ----
    {
        uint4 a, b;
        load_x32(xf, xbf, use_xbf, ((size_t)(0 * BATCH + bgrow)) * xstride + scol * 16, a, b);
        *(uint4*)&comb[srow][scol * 16]     = a;
        *(uint4*)&comb[srow][scol * 16 + 8] = b;
        uint4 z = {0u, 0u, 0u, 0u};
        *(uint4*)&comb[srow][512 + scol * 16]     = z;
        *(uint4*)&comb[srow][512 + scol * 16 + 8] = z;
    }
    __syncthreads();

    // ---- x-MFMA for t=0 ----
    f32x4 axa = {0.f, 0.f, 0.f, 0.f}, axb = {0.f, 0.f, 0.f, 0.f};
#pragma unroll
    for (int kk = 0; kk < 16; kk += 2) {
        bf16x8 a0 = *(const bf16x8*)&comb[n][kk * 32 + quad * 8];
        bf16x8 a1 = *(const bf16x8*)&comb[n][(kk + 1) * 32 + quad * 8];
        axa = __builtin_amdgcn_mfma_f32_16x16x32_bf16(a0, wfr[kk],     axa, 0, 0, 0);
        axb = __builtin_amdgcn_mfma_f32_16x16x32_bf16(a1, wfr[kk + 1], axb, 0, 0, 0);
    }

    // ---- prefetch x_1 into registers ----
    uint4 pfa, pfb;
    load_x32(xf, xbf, use_xbf, ((size_t)(1 * BATCH + bgrow)) * xstride + scol * 16, pfa, pfb);

    // pre-issued h packets (filled at the end of each step for the next one)
    unsigned long long pv[8];

    for (int t = 0; t < T_STEPS; ++t) {
        // ---- phase A: tagged-packet poll for h_{t-1}, stage to LDS ----
        if (t > 0) {
            const unsigned long long* hs = hbuf + (size_t)((t - 1) & 1) * HPAIRS
                                         + (size_t)bgrow * 256 + (size_t)scol * 8;
            const unsigned int want = (unsigned int)t;   // producer at t-1 stored tag t
            bool ok = true;
#pragma unroll
            for (int j = 0; j < 8; ++j) ok = ok && ((unsigned int)(pv[j] >> 32) == want);
            while (!ok) {
#pragma unroll
                for (int j = 0; j < 8; ++j)
                    pv[j] = __hip_atomic_load(hs + j, __ATOMIC_RELAXED, __HIP_MEMORY_SCOPE_AGENT);
                ok = true;
#pragma unroll
                for (int j = 0; j < 8; ++j) ok = ok && ((unsigned int)(pv[j] >> 32) == want);
            }
            uint4 a, b;
            a.x = (unsigned int)pv[0]; a.y = (unsigned int)pv[1];
            a.z = (unsigned int)pv[2]; a.w = (unsigned int)pv[3];
            b.x = (unsigned int)pv[4]; b.y = (unsigned int)pv[5];
            b.z = (unsigned int)pv[6]; b.w = (unsigned int)pv[7];
            *(uint4*)&comb[srow][512 + scol * 16]     = a;
            *(uint4*)&comb[srow][512 + scol * 16 + 8] = b;
        }
        __syncthreads();   // barrier 1: h_{t-1} staged (t=0: zeros from prologue)

        // ---- phase B: h-MFMA accumulates onto the x-partials from last iteration ----
#pragma unroll
        for (int kk = 16; kk < 32; kk += 2) {
            bf16x8 a0 = *(const bf16x8*)&comb[n][kk * 32 + quad * 8];
            bf16x8 a1 = *(const bf16x8*)&comb[n][(kk + 1) * 32 + quad * 8];
            axa = __builtin_amdgcn_mfma_f32_16x16x32_bf16(a0, wfr[kk],     axa, 0, 0, 0);
            axb = __builtin_amdgcn_mfma_f32_16x16x32_bf16(a1, wfr[kk + 1], axb, 0, 0, 0);
        }

        // ---- activations -> LDS gate exchange; also stage x_{t+1} from regs ----
#pragma unroll
        for (int r = 0; r < 4; ++r) {
            float v = axa[r] + axb[r] + bias;
            v = (gate == 2) ? tanhf_(v) : sigmoidf_(v);
            gatesl[gate][quad * 4 + r][uh * 16 + n] = v;
        }
        if (t + 1 < T_STEPS) {
            *(uint4*)&comb[srow][scol * 16]     = pfa;
            *(uint4*)&comb[srow][scol * 16 + 8] = pfb;
        }
        __syncthreads();   // barrier 2: gates + x_{t+1} staged

        // ---- phase C: LSTM cell (c in register); publish tagged h_t; out store ----
        {
            float fv = gatesl[0][bc][uc], iv = gatesl[1][bc][uc];
            float gv = gatesl[2][bc][uc], ov = gatesl[3][bc][uc];
            float cn = fv * creg + iv * gv;
            creg = cn;
            float hv = ov * tanhf_(cn);
            // packed-pair tagged publish: {tag=t+1, 2x bf16}; fire-and-forget
            unsigned int us  = (unsigned int)f2bf(hv);
            unsigned int us1 = (unsigned int)__shfl_down((int)us, 1);
            if (t + 1 < T_STEPS && (uc & 1) == 0) {
                unsigned long long pkt = ((unsigned long long)(unsigned int)(t + 1) << 32)
                                       | (unsigned long long)(us | (us1 << 16));
                unsigned long long* hp = hbuf + (size_t)(t & 1) * HPAIRS
                                       + (size_t)bglob * 256 + (size_t)(uglob >> 1);
                __hip_atomic_store(hp, pkt, __ATOMIC_RELAXED, __HIP_MEMORY_SCOPE_AGENT);
            }
            out[(size_t)t * BATCH * HID + (size_t)bglob * HID + uglob] = hv;
            if (t == T_STEPS - 1) {
                out[(size_t)T_STEPS * BATCH * HID + (size_t)bglob * HID + uglob] = hv;                 // hx
                out[(size_t)T_STEPS * BATCH * HID + BATCH * HID + (size_t)bglob * HID + uglob] = cn;   // cx
            }
        }

        // ---- x-MFMA for t+1 (overlaps the publish drain) ----
        if (t + 1 < T_STEPS) {
            axa = (f32x4){0.f, 0.f, 0.f, 0.f};
            axb = (f32x4){0.f, 0.f, 0.f, 0.f};
#pragma unroll
            for (int kk = 0; kk < 16; kk += 2) {
                bf16x8 a0 = *(const bf16x8*)&comb[n][kk * 32 + quad * 8];
                bf16x8 a1 = *(const bf16x8*)&comb[n][(kk + 1) * 32 + quad * 8];
                axa = __builtin_amdgcn_mfma_f32_16x16x32_bf16(a0, wfr[kk],     axa, 0, 0, 0);
                axb = __builtin_amdgcn_mfma_f32_16x16x32_bf16(a1, wfr[kk + 1], axb, 0, 0, 0);
            }
        }

        // ---- prefetch x_{t+2}; pre-issue next step's h-packet loads ----
        if (t + 2 < T_STEPS) {
            load_x32(xf, xbf, use_xbf,
                     ((size_t)((t + 2) * BATCH + bgrow)) * xstride + scol * 16, pfa, pfb);
        }
        if (t + 1 < T_STEPS) {
            const unsigned long long* hs2 = hbuf + (size_t)(t & 1) * HPAIRS
                                          + (size_t)bgrow * 256 + (size_t)scol * 8;
#pragma unroll
            for (int j = 0; j < 8; ++j)
                pv[j] = __hip_atomic_load(hs2 + j, __ATOMIC_RELAXED, __HIP_MEMORY_SCOPE_AGENT);
        }
    }
}

extern "C" void kernel_launch(void* const* d_in, const int* in_sizes, int n_in,
                              void* d_out, int out_size, void* d_ws, size_t ws_size,
                              hipStream_t stream) {
    (void)in_sizes; (void)n_in; (void)out_size;
    const float* x   = (const float*)d_in[0];
    const float* Wf  = (const float*)d_in[1];
    const float* bfv = (const float*)d_in[2];
    const float* Wi  = (const float*)d_in[3];
    const float* biv = (const float*)d_in[4];
    const float* Wg  = (const float*)d_in[5];
    const float* bgv = (const float*)d_in[6];
    const float* Wo  = (const float*)d_in[7];
    const float* bov = (const float*)d_in[8];
    float* out = (float*)d_out;

    unsigned char* ws = (unsigned char*)d_ws;
    unsigned long long* hbuf = (unsigned long long*)ws;               // 2*128*256*8 = 512 KB
    unsigned short*     xbf  = (unsigned short*)(ws + 524288);        // 64 MB (optional)

    size_t need = 524288 + (size_t)T_STEPS * BATCH * HID * 2;
    int use_xbf = (ws_size >= need) ? 1 : 0;

    // zero the packet tags (stale tags from a previous/killed launch must not match)
    hipMemsetAsync(hbuf, 0, 524288, stream);
    if (use_xbf) {
        int nelem = T_STEPS * BATCH * HID;
        cast_x_kernel<<<nelem / (256 * 8), 256, 0, stream>>>(x, xbf, nelem);
    }
    lstm_kernel<<<dim3(128), dim3(512), 0, stream>>>(
        x, xbf, Wf, bfv, Wi, biv, Wg, bgv, Wo, bov, out, hbuf, use_xbf);
}